// Round 6
// baseline (996.458 us; speedup 1.0000x reference)
//
#include <hip/hip_runtime.h>
#include <math.h>
#include <stdint.h>

#define T_DATA 20000
#define E_NO   2000
#define I_NO   500
#define SUB    16
#define TNO    200
#define NBLK   313   // ceil(20000/64)

// ---------------- workspace layout (float offsets) ----------------
// 0       ek[3200]   (s*200+t)
// 3200    ik[3200]
// 6400    hist[200]
// 6600    ewsub[16]
// 6616    we[2000]
// 8616    wi[500]
// 16384   synE[20000*16]
// 336384  synI[20000*16]
// 656384  negd[20000]
// 676384  me[2000] (int)
// 678384  mi[500]  (int)
// 678884  cmask[16](int)

// ---------------------------------------------------------------------------
// K1: per-subunit kernels, hist kernel, synapse->subunit maps, tree masks.
// ---------------------------------------------------------------------------
__global__ __launch_bounds__(256) void k_prep(
    const float* __restrict__ Ce, const float* __restrict__ Ci,
    const float* __restrict__ cosb,
    const float* __restrict__ TauE, const float* __restrict__ TauI,
    const float* __restrict__ We,  const float* __restrict__ Wi,
    const float* __restrict__ De,  const float* __restrict__ Di,
    const float* __restrict__ Wsub, const float* __restrict__ Whist,
    const int* __restrict__ Cden,
    float* __restrict__ ws_ek, float* __restrict__ ws_ik,
    float* __restrict__ ws_hist, float* __restrict__ ws_ewsub,
    float* __restrict__ ws_we, float* __restrict__ ws_wi,
    int* __restrict__ ws_me, int* __restrict__ ws_mi, int* __restrict__ ws_cmask,
    float* __restrict__ out_filt) {
  int tid = threadIdx.x;
  for (int idx = tid; idx < SUB * TNO; idx += 256) {
    int s = idx / TNO;
    float tf = (float)(idx % TNO);
    float te  = fmaxf(tf - expf(De[s]), 0.f);
    float tte = te / expf(TauE[s]);
    float ekv = tte * expf(-tte) * expf(We[s]);
    float ti_ = fmaxf(tf - expf(Di[s]), 0.f);
    float tti = ti_ / expf(TauI[s]);
    float ikv = -(tti * expf(-tti) * expf(Wi[s]));
    ws_ek[idx] = ekv;
    ws_ik[idx] = ikv;
    out_filt[idx] = ekv;            // rows 0..15
    out_filt[3200 + idx] = ikv;     // rows 16..31
  }
  for (int t = tid; t < TNO; t += 256) {
    float h = 0.f;
    for (int b = 0; b < 16; ++b) h = fmaf(Whist[b], cosb[b * TNO + t], h);
    ws_hist[t] = h;
    out_filt[6400 + t] = h;         // row 32 (unflipped)
  }
  for (int e = tid; e < E_NO; e += 256) {
    int m = 0; float w = 0.f;
    for (int s = 0; s < SUB; ++s) {
      float v = Ce[s * E_NO + e];
      if (w == 0.f && v != 0.f) { m = s; w = v; }
    }
    ws_me[e] = m; ws_we[e] = w;
  }
  for (int e = tid; e < I_NO; e += 256) {
    int m = 0; float w = 0.f;
    for (int s = 0; s < SUB; ++s) {
      float v = Ci[s * I_NO + e];
      if (w == 0.f && v != 0.f) { m = s; w = v; }
    }
    ws_mi[e] = m; ws_wi[e] = w;
  }
  if (tid < SUB) {
    ws_ewsub[tid] = expf(Wsub[tid]);
    int msk = 0;
    for (int j = 0; j < SUB; ++j)
      if (Cden[tid * SUB + j] == 1) msk |= (1 << j);
    ws_cmask[tid] = msk;
  }
}

// ---------------------------------------------------------------------------
// K2: synapse aggregation -> synE/synI [20000][16]. Deterministic.
// ---------------------------------------------------------------------------
__global__ __launch_bounds__(256) void k_agg(
    const float4* __restrict__ Se4, const float4* __restrict__ Si4,
    const int* __restrict__ me, const float* __restrict__ we,
    const int* __restrict__ mi, const float* __restrict__ wi,
    float* __restrict__ synE, float* __restrict__ synI) {
  __shared__ float bins[4][64][33];
  int tid = threadIdx.x, wid = tid >> 6, l = tid & 63;
  int gw = blockIdx.x * 4 + wid;
  for (int r = 0; r < 4; ++r) {
    int t = gw * 4 + r;
#pragma unroll
    for (int s = 0; s < 32; ++s) bins[wid][l][s] = 0.f;
    for (int i = 0; i < 8; ++i) {
      int idx = i * 64 + l;
      if (idx < 500) {
        float4 v = Se4[(size_t)t * 500 + idx];
        int e0 = idx * 4;
        if (v.x != 0.f) bins[wid][l][me[e0 + 0]] += v.x * we[e0 + 0];
        if (v.y != 0.f) bins[wid][l][me[e0 + 1]] += v.y * we[e0 + 1];
        if (v.z != 0.f) bins[wid][l][me[e0 + 2]] += v.z * we[e0 + 2];
        if (v.w != 0.f) bins[wid][l][me[e0 + 3]] += v.w * we[e0 + 3];
      }
    }
    for (int i = 0; i < 2; ++i) {
      int idx = i * 64 + l;
      if (idx < 125) {
        float4 v = Si4[(size_t)t * 125 + idx];
        int e0 = idx * 4;
        if (v.x != 0.f) bins[wid][l][16 + mi[e0 + 0]] += v.x * wi[e0 + 0];
        if (v.y != 0.f) bins[wid][l][16 + mi[e0 + 1]] += v.y * wi[e0 + 1];
        if (v.z != 0.f) bins[wid][l][16 + mi[e0 + 2]] += v.z * wi[e0 + 2];
        if (v.w != 0.f) bins[wid][l][16 + mi[e0 + 3]] += v.w * wi[e0 + 3];
      }
    }
    __syncthreads();
    if (l < 32) {
      float a = 0.f;
      for (int k = 0; k < 64; ++k) a += bins[wid][k][l];
      if (l < 16) synE[(size_t)t * 16 + l] = a;
      else        synI[(size_t)t * 16 + (l - 16)] = a;
    }
    __syncthreads();
  }
}

// ---------------------------------------------------------------------------
// K3: causal filtering + dendritic tree -> negd[t] = -drive[t].
// ---------------------------------------------------------------------------
__global__ __launch_bounds__(64) void k_filt(
    const float* __restrict__ synE, const float* __restrict__ synI,
    const float* __restrict__ ek_ws, const float* __restrict__ ik_ws,
    const float* __restrict__ theta, const float* __restrict__ ewsub,
    const int* __restrict__ cmask,
    float* __restrict__ negd) {
  __shared__ float sE[264 * 17];
  __shared__ float sI[264 * 17];
  __shared__ float ekl[TNO * 16];
  __shared__ float ikl[TNO * 16];
  int l = threadIdx.x;
  int t0 = blockIdx.x * 64;
  for (int idx = l; idx < 264 * 16; idx += 64) {
    int row = idx >> 4, s = idx & 15;
    int g = t0 - 200 + row;
    bool ok = (g >= 0) && (g < T_DATA);
    sE[row * 17 + s] = ok ? synE[(size_t)g * 16 + s] : 0.f;
    sI[row * 17 + s] = ok ? synI[(size_t)g * 16 + s] : 0.f;
  }
  for (int idx = l; idx < SUB * TNO; idx += 64) {
    int s = idx / TNO, j = idx % TNO;
    ekl[j * 16 + s] = ek_ws[idx];
    ikl[j * 16 + s] = ik_ws[idx];
  }
  __syncthreads();
  int t = t0 + l;
  float acc[16];
#pragma unroll
  for (int s = 0; s < 16; ++s) acc[s] = 0.f;
  for (int j = 0; j < TNO; ++j) {
    int base = (l + 199 - j) * 17;
    int kb = j * 16;
#pragma unroll
    for (int s = 0; s < 16; ++s)
      acc[s] = fmaf(ekl[kb + s], sE[base + s], fmaf(ikl[kb + s], sI[base + s], acc[s]));
  }
  float th[16], ew[16]; int cm[16];
#pragma unroll
  for (int s = 0; s < 16; ++s) { th[s] = theta[s]; ew[s] = ewsub[s]; cm[s] = cmask[s]; }
  float val[16];
#pragma unroll
  for (int s = 0; s < 16; ++s) val[s] = 0.f;
#pragma unroll
  for (int sidx = 15; sidx >= 1; --sidx) {
    float sum = acc[sidx] + th[sidx];
#pragma unroll
    for (int j = 0; j < 16; ++j)
      if ((cm[sidx] >> j) & 1) sum += val[j] * ew[j];
    val[sidx] = tanhf(sum);
  }
  float drive = acc[0] + th[0];
#pragma unroll
  for (int j = 0; j < 16; ++j)
    if ((cm[0] >> j) & 1) drive += val[j] * ew[j];
  if (t < T_DATA) negd[t] = -drive;
}

// ---------------------------------------------------------------------------
// K4: sequential spike scan. 1 workgroup, 4 waves (one per SIMD).
// ROUND 6: rounds 2-5 proved wave0 was NOT critical (identical 765us across
// three wave0 rewrites). Critical path was the deep waves' rolled loop:
// 46 iters x ~120cyc single-outstanding ds_read latency = ~5500cyc/block.
// Fix: spikes published as per-block u64 BITMASKS (mring ring); deep waves
// read 3 broadcast masks/block, hoist to SGPR, and run a fully static-
// unrolled tap sequence against register-held hd0..hd45 (block-invariant).
// Wave0: chain keeps h0..h63 in regs; boundary conv reads hpad from LDS
// (64 independent unrolled ds_reads, batched, off the serial chain).
// ---------------------------------------------------------------------------
__global__
__attribute__((amdgpu_flat_work_group_size(256, 256), amdgpu_waves_per_eu(1, 1)))
void k_scan(
    const float* __restrict__ hist, const float* __restrict__ negd,
    float* __restrict__ out_spk) {
  __shared__ float hpad[328];        // [0..63]=0, [64..263]=h[0..199], [264..327]=0
  __shared__ unsigned long long mring[8];  // per-block spike masks, slot n&7
  __shared__ float deepb[2][3][64];  // parity double-buffered deep partials
  int tid = threadIdx.x, wid = tid >> 6, l = tid & 63;
  for (int i = tid; i < 328; i += 256) hpad[i] = (i >= 64 && i < 264) ? hist[i - 64] : 0.f;
  if (tid < 8) mring[tid] = 0ull;
  for (int i = tid; i < 2 * 3 * 64; i += 256) (&deepb[0][0][0])[i] = 0.f;
  __syncthreads();

  // wave0 chain registers: h(j) = hpad[l + j], j in [0,64)
  float h0=0,h1=0,h2=0,h3=0,h4=0,h5=0,h6=0,h7=0,h8=0,h9=0,h10=0,h11=0,h12=0,h13=0,h14=0,h15=0,
        h16=0,h17=0,h18=0,h19=0,h20=0,h21=0,h22=0,h23=0,h24=0,h25=0,h26=0,h27=0,h28=0,h29=0,h30=0,h31=0,
        h32=0,h33=0,h34=0,h35=0,h36=0,h37=0,h38=0,h39=0,h40=0,h41=0,h42=0,h43=0,h44=0,h45=0,h46=0,h47=0,
        h48=0,h49=0,h50=0,h51=0,h52=0,h53=0,h54=0,h55=0,h56=0,h57=0,h58=0,h59=0,h60=0,h61=0,h62=0,h63=0;
  // deep-wave tap registers: hd(j) = hpad[dbase + l + j], j in [0,46)
  float hd0=0,hd1=0,hd2=0,hd3=0,hd4=0,hd5=0,hd6=0,hd7=0,hd8=0,hd9=0,hd10=0,hd11=0,hd12=0,hd13=0,hd14=0,hd15=0,
        hd16=0,hd17=0,hd18=0,hd19=0,hd20=0,hd21=0,hd22=0,hd23=0,hd24=0,hd25=0,hd26=0,hd27=0,hd28=0,hd29=0,hd30=0,hd31=0,
        hd32=0,hd33=0,hd34=0,hd35=0,hd36=0,hd37=0,hd38=0,hd39=0,hd40=0,hd41=0,hd42=0,hd43=0,hd44=0,hd45=0;
  if (wid == 0) {
#define LD(j) h##j = hpad[l + j];
    LD(0)LD(1)LD(2)LD(3)LD(4)LD(5)LD(6)LD(7)LD(8)LD(9)LD(10)LD(11)LD(12)LD(13)LD(14)LD(15)
    LD(16)LD(17)LD(18)LD(19)LD(20)LD(21)LD(22)LD(23)LD(24)LD(25)LD(26)LD(27)LD(28)LD(29)LD(30)LD(31)
    LD(32)LD(33)LD(34)LD(35)LD(36)LD(37)LD(38)LD(39)LD(40)LD(41)LD(42)LD(43)LD(44)LD(45)LD(46)LD(47)
    LD(48)LD(49)LD(50)LD(51)LD(52)LD(53)LD(54)LD(55)LD(56)LD(57)LD(58)LD(59)LD(60)LD(61)LD(62)LD(63)
#undef LD
  } else {
    int dbase = (wid == 2) ? 174 : (wid == 3) ? 219 : 128;
#define LHD(j) hd##j = hpad[dbase + l + j];
    LHD(0)LHD(1)LHD(2)LHD(3)LHD(4)LHD(5)LHD(6)LHD(7)LHD(8)LHD(9)LHD(10)LHD(11)LHD(12)LHD(13)LHD(14)LHD(15)
    LHD(16)LHD(17)LHD(18)LHD(19)LHD(20)LHD(21)LHD(22)LHD(23)LHD(24)LHD(25)LHD(26)LHD(27)LHD(28)LHD(29)LHD(30)LHD(31)
    LHD(32)LHD(33)LHD(34)LHD(35)LHD(36)LHD(37)LHD(38)LHD(39)LHD(40)LHD(41)LHD(42)LHD(43)LHD(44)LHD(45)
#undef LHD
  }

  unsigned long long mask_prev = 0ull;
  float ndv = (wid == 0) ? negd[l] : 0.f;

  for (int n = 0; n < NBLK; ++n) {
    int t0 = n * 64;
    if (wid == 0) {
      int tn = t0 + 64 + l;
      float ndnext = (tn < T_DATA) ? negd[tn] : INFINITY;
      int par = n & 1;
      float X = deepb[par][0][l] + deepb[par][1][l] + deepb[par][2][l];
      // boundary conv: tap i adds hpad[127+l-i] when prev-block bit i set.
      // Unrolled LDS reads: 64 independent ds_reads, issue-batched, not on
      // the serial chain.
      {
        float a0 = 0.f, a1 = 0.f, a2 = 0.f, a3 = 0.f;
#pragma unroll
        for (int i = 0; i < 64; i += 4) {
          a0 = fmaf((float)((mask_prev >> (i + 0)) & 1ull), hpad[127 + l - (i + 0)], a0);
          a1 = fmaf((float)((mask_prev >> (i + 1)) & 1ull), hpad[127 + l - (i + 1)], a1);
          a2 = fmaf((float)((mask_prev >> (i + 2)) & 1ull), hpad[127 + l - (i + 2)], a2);
          a3 = fmaf((float)((mask_prev >> (i + 3)) & 1ull), hpad[127 + l - (i + 3)], a3);
        }
        X += (a0 + a1) + (a2 + a3);
      }
      // sequential chain: step i adds h(63-i) when bit i fires
      unsigned long long msk = 0ull;
#define CH(i, hv) { unsigned long long bm = __ballot(X > ndv); \
                    X = fmaf((float)((bm >> (i)) & 1ull), hv, X); \
                    msk |= (bm & (1ull << (i))); }
      CH(0,h63)CH(1,h62)CH(2,h61)CH(3,h60)CH(4,h59)CH(5,h58)CH(6,h57)CH(7,h56)
      CH(8,h55)CH(9,h54)CH(10,h53)CH(11,h52)CH(12,h51)CH(13,h50)CH(14,h49)CH(15,h48)
      CH(16,h47)CH(17,h46)CH(18,h45)CH(19,h44)CH(20,h43)CH(21,h42)CH(22,h41)CH(23,h40)
      CH(24,h39)CH(25,h38)CH(26,h37)CH(27,h36)CH(28,h35)CH(29,h34)CH(30,h33)CH(31,h32)
      CH(32,h31)CH(33,h30)CH(34,h29)CH(35,h28)CH(36,h27)CH(37,h26)CH(38,h25)CH(39,h24)
      CH(40,h23)CH(41,h22)CH(42,h21)CH(43,h20)CH(44,h19)CH(45,h18)CH(46,h17)CH(47,h16)
      CH(48,h15)CH(49,h14)CH(50,h13)CH(51,h12)CH(52,h11)CH(53,h10)CH(54,h9)CH(55,h8)
      CH(56,h7)CH(57,h6)CH(58,h5)CH(59,h4)CH(60,h3)CH(61,h2)CH(62,h1)CH(63,h0)
#undef CH
      // publish: spike output + block mask
      float myspk = (float)((msk >> l) & 1ull);
      int t = t0 + l;
      if (t < T_DATA) out_spk[t] = myspk;
      if (l == 0) mring[n & 7] = msk;
      mask_prev = msk;
      ndv = ndnext;
    } else {
      // deep feedback for block n+1 from spike bitmasks of blocks n-1..n-3.
      // wave w handles k = k0_w + j: tap hd(j) = hpad[128+k0_w + l + j];
      // bit: k<64 -> (63-k) of M1; k<128 -> (127-k) of M2; else (191-k) of M3.
      unsigned long long M1 = mring[(n + 7) & 7];
      unsigned long long M2 = mring[(n + 6) & 7];
      unsigned long long M3 = mring[(n + 5) & 7];
      M1 = ((unsigned long long)__builtin_amdgcn_readfirstlane((unsigned)(M1 >> 32)) << 32)
           | (unsigned)__builtin_amdgcn_readfirstlane((unsigned)M1);
      M2 = ((unsigned long long)__builtin_amdgcn_readfirstlane((unsigned)(M2 >> 32)) << 32)
           | (unsigned)__builtin_amdgcn_readfirstlane((unsigned)M2);
      M3 = ((unsigned long long)__builtin_amdgcn_readfirstlane((unsigned)(M3 >> 32)) << 32)
           | (unsigned)__builtin_amdgcn_readfirstlane((unsigned)M3);
      float a0 = 0.f, a1 = 0.f, a2 = 0.f, a3 = 0.f;
#define DT(j, M, b, acc) acc = fmaf((float)(((M) >> (b)) & 1ull), hd##j, acc);
      if (wid == 1) {
        // k = j in [0,46): all M1, bit 63-j
        DT(0,M1,63,a0)DT(1,M1,62,a1)DT(2,M1,61,a2)DT(3,M1,60,a3)
        DT(4,M1,59,a0)DT(5,M1,58,a1)DT(6,M1,57,a2)DT(7,M1,56,a3)
        DT(8,M1,55,a0)DT(9,M1,54,a1)DT(10,M1,53,a2)DT(11,M1,52,a3)
        DT(12,M1,51,a0)DT(13,M1,50,a1)DT(14,M1,49,a2)DT(15,M1,48,a3)
        DT(16,M1,47,a0)DT(17,M1,46,a1)DT(18,M1,45,a2)DT(19,M1,44,a3)
        DT(20,M1,43,a0)DT(21,M1,42,a1)DT(22,M1,41,a2)DT(23,M1,40,a3)
        DT(24,M1,39,a0)DT(25,M1,38,a1)DT(26,M1,37,a2)DT(27,M1,36,a3)
        DT(28,M1,35,a0)DT(29,M1,34,a1)DT(30,M1,33,a2)DT(31,M1,32,a3)
        DT(32,M1,31,a0)DT(33,M1,30,a1)DT(34,M1,29,a2)DT(35,M1,28,a3)
        DT(36,M1,27,a0)DT(37,M1,26,a1)DT(38,M1,25,a2)DT(39,M1,24,a3)
        DT(40,M1,23,a0)DT(41,M1,22,a1)DT(42,M1,21,a2)DT(43,M1,20,a3)
        DT(44,M1,19,a0)DT(45,M1,18,a1)
      } else if (wid == 2) {
        // k = 46+j, j in [0,45): j<18 -> M1 bit 17-j; else M2 bit 81-j
        DT(0,M1,17,a0)DT(1,M1,16,a1)DT(2,M1,15,a2)DT(3,M1,14,a3)
        DT(4,M1,13,a0)DT(5,M1,12,a1)DT(6,M1,11,a2)DT(7,M1,10,a3)
        DT(8,M1,9,a0)DT(9,M1,8,a1)DT(10,M1,7,a2)DT(11,M1,6,a3)
        DT(12,M1,5,a0)DT(13,M1,4,a1)DT(14,M1,3,a2)DT(15,M1,2,a3)
        DT(16,M1,1,a0)DT(17,M1,0,a1)
        DT(18,M2,63,a2)DT(19,M2,62,a3)
        DT(20,M2,61,a0)DT(21,M2,60,a1)DT(22,M2,59,a2)DT(23,M2,58,a3)
        DT(24,M2,57,a0)DT(25,M2,56,a1)DT(26,M2,55,a2)DT(27,M2,54,a3)
        DT(28,M2,53,a0)DT(29,M2,52,a1)DT(30,M2,51,a2)DT(31,M2,50,a3)
        DT(32,M2,49,a0)DT(33,M2,48,a1)DT(34,M2,47,a2)DT(35,M2,46,a3)
        DT(36,M2,45,a0)DT(37,M2,44,a1)DT(38,M2,43,a2)DT(39,M2,42,a3)
        DT(40,M2,41,a0)DT(41,M2,40,a1)DT(42,M2,39,a2)DT(43,M2,38,a3)
        DT(44,M2,37,a0)
      } else {
        // k = 91+j, j in [0,45): j<37 -> M2 bit 36-j; else M3 bit 100-j
        DT(0,M2,36,a0)DT(1,M2,35,a1)DT(2,M2,34,a2)DT(3,M2,33,a3)
        DT(4,M2,32,a0)DT(5,M2,31,a1)DT(6,M2,30,a2)DT(7,M2,29,a3)
        DT(8,M2,28,a0)DT(9,M2,27,a1)DT(10,M2,26,a2)DT(11,M2,25,a3)
        DT(12,M2,24,a0)DT(13,M2,23,a1)DT(14,M2,22,a2)DT(15,M2,21,a3)
        DT(16,M2,20,a0)DT(17,M2,19,a1)DT(18,M2,18,a2)DT(19,M2,17,a3)
        DT(20,M2,16,a0)DT(21,M2,15,a1)DT(22,M2,14,a2)DT(23,M2,13,a3)
        DT(24,M2,12,a0)DT(25,M2,11,a1)DT(26,M2,10,a2)DT(27,M2,9,a3)
        DT(28,M2,8,a0)DT(29,M2,7,a1)DT(30,M2,6,a2)DT(31,M2,5,a3)
        DT(32,M2,4,a0)DT(33,M2,3,a1)DT(34,M2,2,a2)DT(35,M2,1,a3)
        DT(36,M2,0,a0)
        DT(37,M3,63,a1)DT(38,M3,62,a2)DT(39,M3,61,a3)
        DT(40,M3,60,a0)DT(41,M3,59,a1)DT(42,M3,58,a2)DT(43,M3,57,a3)
        DT(44,M3,56,a0)
      }
#undef DT
      deepb[(n + 1) & 1][wid - 1][l] = (a0 + a1) + (a2 + a3);
    }
    __syncthreads();
  }
}

// ---------------------------------------------------------------------------
extern "C" void kernel_launch(void* const* d_in, const int* in_sizes, int n_in,
                              void* d_out, int out_size, void* d_ws, size_t ws_size,
                              hipStream_t stream) {
  const float* S_e      = (const float*)d_in[0];
  const float* S_i      = (const float*)d_in[1];
  const int*   C_den    = (const int*)d_in[2];
  const float* C_syn_e  = (const float*)d_in[3];
  const float* C_syn_i  = (const float*)d_in[4];
  const float* cos_b    = (const float*)d_in[5];
  const float* Tau_e    = (const float*)d_in[6];
  const float* Tau_i    = (const float*)d_in[7];
  const float* W_e      = (const float*)d_in[8];
  const float* W_i      = (const float*)d_in[9];
  const float* D_e      = (const float*)d_in[10];
  const float* D_i      = (const float*)d_in[11];
  const float* W_sub    = (const float*)d_in[12];
  const float* W_hist   = (const float*)d_in[13];
  const float* Theta    = (const float*)d_in[14];
  float* out = (float*)d_out;

  float* wsf      = (float*)d_ws;
  float* ws_ek    = wsf;
  float* ws_ik    = wsf + 3200;
  float* ws_hist  = wsf + 6400;
  float* ws_ewsub = wsf + 6600;
  float* ws_we    = wsf + 6616;
  float* ws_wi    = wsf + 8616;
  float* synE     = wsf + 16384;
  float* synI     = wsf + 336384;
  float* negd     = wsf + 656384;
  int*   ws_me    = (int*)(wsf + 676384);
  int*   ws_mi    = (int*)(wsf + 678384);
  int*   ws_cmask = (int*)(wsf + 678884);

  k_prep<<<dim3(1), dim3(256), 0, stream>>>(
      C_syn_e, C_syn_i, cos_b, Tau_e, Tau_i, W_e, W_i, D_e, D_i, W_sub, W_hist,
      C_den, ws_ek, ws_ik, ws_hist, ws_ewsub, ws_we, ws_wi, ws_me, ws_mi,
      ws_cmask, out + T_DATA);

  k_agg<<<dim3(1250), dim3(256), 0, stream>>>(
      (const float4*)S_e, (const float4*)S_i, ws_me, ws_we, ws_mi, ws_wi,
      synE, synI);

  k_filt<<<dim3(NBLK), dim3(64), 0, stream>>>(
      synE, synI, ws_ek, ws_ik, Theta, ws_ewsub, ws_cmask, negd);

  k_scan<<<dim3(1), dim3(256), 0, stream>>>(ws_hist, negd, out);
}